// Round 6
// baseline (182.194 us; speedup 1.0000x reference)
//
#include <hip/hip_runtime.h>

#define BATCH 4
#define T 4096
#define D 128
#define CHUNKS 64              // gram chunks per batch (64 rows each)
#define ROWS 64                // rows per block tile
#define ST1 72                 // XT LDS stride in ushorts (144 B = 36 words ≡ 4 mod 32)
#define S2 136                 // phase-C LDS stride in ushorts (272 B)
#define NBLK (BATCH * CHUNKS)  // 256 blocks, 1 per CU -> co-resident (grid barrier safe)

typedef __attribute__((ext_vector_type(4))) float f32x4;
typedef __attribute__((ext_vector_type(8))) short bf16x8;

__device__ __forceinline__ unsigned short f2b(float f) {
    unsigned u = __builtin_bit_cast(unsigned, f);
    u += 0x7FFFu + ((u >> 16) & 1u);
    return (unsigned short)(u >> 16);
}
__device__ __forceinline__ float b2f(unsigned short h) {
    return __builtin_bit_cast(float, (unsigned)h << 16);
}

// Device-scope grid barrier. Safe because all NBLK blocks are co-resident
// (1 block/CU; 52 KB LDS < 64 KB, VGPR well under budget). Counter zeroed by
// hipMemsetAsync each launch (ws is re-poisoned 0xAA by the harness).
__device__ __forceinline__ void grid_barrier(unsigned* ctr, int tid) {
    __syncthreads();
    __threadfence();                         // release: partials visible device-wide
    if (tid == 0) {
        atomicAdd(ctr, 1u);
        while (atomicAdd(ctr, 0u) < NBLK)    // RMW load: coherent, not hoistable
            __builtin_amdgcn_s_sleep(1);
    }
    __syncthreads();
    __threadfence();                         // acquire: remote writes visible to all lanes
}

// ---------------- Fused: gram -> reduce -> X*G, one dispatch -----------------
// Phase A: block (b,chunk) computes 64-row partial Gram via bf16 MFMA into
//   ws raw C-fragment order (per-thread contiguous 128 B -> coalesced stores).
// Phase B: thread o reduces its G element over 64 chunks (coalesced 2B reads),
//   applies the inverse fragment map, writes row-major bf16 G.
// Phase C: block (b,chunk) computes the 64x128 output tile via bf16 MFMA
//   (round-4-proven structure: G symmetric -> B-frag reads G row-major).
__global__ __launch_bounds__(256) void k_fused(const float* __restrict__ x,
                                               unsigned short* __restrict__ part,
                                               unsigned short* __restrict__ g,
                                               float* __restrict__ out,
                                               unsigned* __restrict__ bar) {
    __shared__ unsigned short smem[(ROWS + D) * S2];   // 52.2 KB, aliased per phase
    const int tid = threadIdx.x;
    const int blk = blockIdx.x;
    const int b = blk >> 6, chunk = blk & 63;
    const float* xp = x + ((size_t)b * T + (size_t)chunk * ROWS) * D;
    const int lane = tid & 63, w = tid >> 6;
    const int m = lane & 15, q = lane >> 4;

    // ---------------- Phase A: partial Gram ----------------
    {
        unsigned short* XT = smem;                      // [D][ST1] transposed bf16
        #pragma unroll
        for (int pass = 0; pass < 8; pass++) {
            const int slot = (tid >> 6) + 4 * pass;
            const int dd = 2 * (tid & 7) + 16 * (slot & 7);
            const int tpg = ((tid >> 3) & 7) + 8 * (slot >> 3);
            const int t = 2 * tpg;
            float2 f0 = *(const float2*)(xp + (size_t)t * D + dd);
            float2 f1 = *(const float2*)(xp + (size_t)(t + 1) * D + dd);
            unsigned u0 = (unsigned)f2b(f0.x) | ((unsigned)f2b(f1.x) << 16);
            unsigned u1 = (unsigned)f2b(f0.y) | ((unsigned)f2b(f1.y) << 16);
            *(unsigned*)(XT + dd * ST1 + 2 * tpg) = u0;
            *(unsigned*)(XT + (dd + 1) * ST1 + 2 * tpg) = u1;
        }
        __syncthreads();

        const int m0 = w * 32;
        f32x4 acc[2][8];
        #pragma unroll
        for (int mi = 0; mi < 2; mi++)
            #pragma unroll
            for (int ni = 0; ni < 8; ni++) acc[mi][ni] = (f32x4){0.f, 0.f, 0.f, 0.f};

        #pragma unroll
        for (int s = 0; s < 2; s++) {
            bf16x8 av[2], bv[8];
            #pragma unroll
            for (int mi = 0; mi < 2; mi++)
                av[mi] = *(const bf16x8*)(XT + (m0 + mi * 16 + m) * ST1 + q * 8 + s * 32);
            #pragma unroll
            for (int ni = 0; ni < 8; ni++)
                bv[ni] = *(const bf16x8*)(XT + (ni * 16 + m) * ST1 + q * 8 + s * 32);
            #pragma unroll
            for (int mi = 0; mi < 2; mi++)
                #pragma unroll
                for (int ni = 0; ni < 8; ni++)
                    acc[mi][ni] = __builtin_amdgcn_mfma_f32_16x16x32_bf16(av[mi], bv[ni], acc[mi][ni], 0, 0, 0);
        }

        // Raw-order store: sub = mi*32 + ni*4 + r; 8x contiguous ushort8 per thread.
        unsigned short* pp = part + (size_t)blk * (D * D) + (size_t)tid * 64;
        #pragma unroll
        for (int j = 0; j < 8; j++) {
            const int mi = j >> 2, nj = (j & 3) * 2;
            ushort4 lo, hi;
            lo.x = f2b(acc[mi][nj][0]);     lo.y = f2b(acc[mi][nj][1]);
            lo.z = f2b(acc[mi][nj][2]);     lo.w = f2b(acc[mi][nj][3]);
            hi.x = f2b(acc[mi][nj + 1][0]); hi.y = f2b(acc[mi][nj + 1][1]);
            hi.z = f2b(acc[mi][nj + 1][2]); hi.w = f2b(acc[mi][nj + 1][3]);
            *(ushort4*)(pp + j * 8) = lo;
            *(ushort4*)(pp + j * 8 + 4) = hi;
        }
    }

    grid_barrier(bar, tid);

    // ---------------- Phase B: reduce -> G (row-major bf16) ----------------
    {
        const int o = blk * 256 + tid;                  // 0 .. BATCH*D*D-1
        const int ob = o >> 14, e = o & 16383;
        const unsigned short* p = part + ((size_t)ob * CHUNKS) * (D * D) + e;
        float s[8];
        #pragma unroll
        for (int i = 0; i < 8; i++) s[i] = 0.f;
        for (int c = 0; c < CHUNKS; c += 8) {
            #pragma unroll
            for (int i = 0; i < 8; i++)
                s[i] += b2f(p[(size_t)(c + i) * (D * D)]);
        }
        float sum = ((s[0] + s[1]) + (s[2] + s[3])) + ((s[4] + s[5]) + (s[6] + s[7]));
        // inverse fragment map: e -> (row, col)
        const int tg = e >> 6, sub = e & 63;
        const int gw = tg >> 6, gl = tg & 63, gm = gl & 15, gq = gl >> 4;
        const int mi = sub >> 5, ni = (sub >> 2) & 7, r = sub & 3;
        const int row = gw * 32 + mi * 16 + gq * 4 + r;
        const int col = ni * 16 + gm;
        g[(size_t)ob * (D * D) + row * D + col] = f2b(sum);
    }

    grid_barrier(bar + 1, tid);

    // ---------------- Phase C: out = X * G ----------------
    {
        unsigned short* Xs = smem;                      // [ROWS][S2]
        unsigned short* Gs = smem + ROWS * S2;          // [D][S2]
        const unsigned short* gp = g + (size_t)b * (D * D);

        {
            const int dg = tid & 31, tr = tid >> 5;
            #pragma unroll
            for (int ii = 0; ii < 8; ii++) {
                const int t = tr + ii * 8;
                float4 v = ((const float4*)(xp + t * D))[dg];
                ushort4 pk;
                pk.x = f2b(v.x); pk.y = f2b(v.y); pk.z = f2b(v.z); pk.w = f2b(v.w);
                *(ushort4*)(Xs + t * S2 + dg * 4) = pk;
            }
        }
        {
            const int f4 = tid & 15, r = tid >> 4;
            #pragma unroll
            for (int ii = 0; ii < 8; ii++) {
                const int row = r + ii * 16;
                uint4 gv = ((const uint4*)(gp + row * D))[f4];
                *(uint4*)(Gs + row * S2 + f4 * 8) = gv;
            }
        }
        __syncthreads();

        f32x4 acc[8];
        #pragma unroll
        for (int ni = 0; ni < 8; ni++) acc[ni] = (f32x4){0.f, 0.f, 0.f, 0.f};

        const unsigned short* arow = Xs + (w * 16 + m) * S2 + q * 8;
        const unsigned short* brow = Gs + m * S2 + q * 8;

        #pragma unroll
        for (int s = 0; s < 4; s++) {
            bf16x8 a = *(const bf16x8*)(arow + s * 32);
            #pragma unroll
            for (int ni = 0; ni < 8; ni++) {
                bf16x8 bb = *(const bf16x8*)(brow + ni * 16 * S2 + s * 32);
                acc[ni] = __builtin_amdgcn_mfma_f32_16x16x32_bf16(a, bb, acc[ni], 0, 0, 0);
            }
        }

        float* op = out + ((size_t)b * T + (size_t)chunk * ROWS) * D;
        const int row0 = w * 16 + q * 4;
        #pragma unroll
        for (int ni = 0; ni < 8; ni++)
            #pragma unroll
            for (int r = 0; r < 4; r++)
                op[(row0 + r) * D + ni * 16 + m] = acc[ni][r];
    }
}

extern "C" void kernel_launch(void* const* d_in, const int* in_sizes, int n_in,
                              void* d_out, int out_size, void* d_ws, size_t ws_size,
                              hipStream_t stream) {
    const float* x = (const float*)d_in[0];
    float* out = (float*)d_out;

    const size_t part_elems = (size_t)NBLK * D * D;               // 4.19M bf16 (8.4 MB)
    const size_t g_elems = (size_t)BATCH * D * D;                 // 64K bf16 (128 KB)
    unsigned short* part = (unsigned short*)d_ws;
    unsigned short* g = part + part_elems;
    unsigned* bar = (unsigned*)(g + g_elems);                     // 2 counters

    hipMemsetAsync(bar, 0, 2 * sizeof(unsigned), stream);         // ws is 0xAA-poisoned
    k_fused<<<NBLK, 256, 0, stream>>>(x, part, g, out, bar);
}

// Round 7
// 89.669 us; speedup vs baseline: 2.0318x; 2.0318x over previous
//
#include <hip/hip_runtime.h>

#define BATCH 4
#define T 4096
#define D 128
#define SLABS 8                // partial-G slabs per batch
#define SROWS 512              // rows per gram slab (K-loop of 8 x 64-row tiles)
#define ROWS 64                // stage-2 rows per block
#define ST1 72                 // XT LDS stride in ushorts (144 B = 36 words ≡ 4 mod 32)
#define S2 136                 // stage-2 LDS stride in ushorts (272 B)

typedef __attribute__((ext_vector_type(4))) float f32x4;
typedef __attribute__((ext_vector_type(8))) short bf16x8;

__device__ __forceinline__ unsigned short f2b(float f) {
    unsigned u = __builtin_bit_cast(unsigned, f);
    u += 0x7FFFu + ((u >> 16) & 1u);
    return (unsigned short)(u >> 16);
}
__device__ __forceinline__ float b2f_lo(unsigned u) {      // low 16 bits
    return __builtin_bit_cast(float, u << 16);
}
__device__ __forceinline__ float b2f_hi(unsigned u) {      // high 16 bits
    return __builtin_bit_cast(float, u & 0xFFFF0000u);
}

// ---------------- Stage 1: slab Gram via bf16 MFMA -----------------
// 32 blocks x 256 threads; block = (batch, 512-row slab). K-loop stages
// 64-row transposed bf16 tiles into LDS (proven round-5 transpose: float2
// pair loads, packed uint writes, <=2-way banks); MFMA accs persist across
// the 8 tiles. Store: row-major bf16 partial G (2B scatter; only 32 blocks).
__global__ __launch_bounds__(256) void k_gram(const float* __restrict__ x,
                                              unsigned short* __restrict__ part) {
    __shared__ unsigned short XT[D * ST1];   // 18.4 KB
    const int blk = blockIdx.x;              // 0..31
    const int b = blk >> 3, slab = blk & 7;
    const float* xp = x + ((size_t)b * T + (size_t)slab * SROWS) * D;
    const int tid = threadIdx.x;
    const int lane = tid & 63, w = tid >> 6;
    const int m = lane & 15, q = lane >> 4;
    const int m0 = w * 32;

    f32x4 acc[2][8];
    #pragma unroll
    for (int mi = 0; mi < 2; mi++)
        #pragma unroll
        for (int ni = 0; ni < 8; ni++) acc[mi][ni] = (f32x4){0.f, 0.f, 0.f, 0.f};

    for (int kt = 0; kt < SROWS / 64; kt++) {
        const float* xk = xp + (size_t)kt * 64 * D;
        if (kt) __syncthreads();             // prior tile's reads done before overwrite
        #pragma unroll
        for (int pass = 0; pass < 8; pass++) {
            const int slot = (tid >> 6) + 4 * pass;
            const int dd = 2 * (tid & 7) + 16 * (slot & 7);
            const int tpg = ((tid >> 3) & 7) + 8 * (slot >> 3);
            const int t = 2 * tpg;
            float2 f0 = *(const float2*)(xk + (size_t)t * D + dd);
            float2 f1 = *(const float2*)(xk + (size_t)(t + 1) * D + dd);
            unsigned u0 = (unsigned)f2b(f0.x) | ((unsigned)f2b(f1.x) << 16);
            unsigned u1 = (unsigned)f2b(f0.y) | ((unsigned)f2b(f1.y) << 16);
            *(unsigned*)(XT + dd * ST1 + 2 * tpg) = u0;
            *(unsigned*)(XT + (dd + 1) * ST1 + 2 * tpg) = u1;
        }
        __syncthreads();

        #pragma unroll
        for (int s = 0; s < 2; s++) {
            bf16x8 av[2], bv[8];
            #pragma unroll
            for (int mi = 0; mi < 2; mi++)
                av[mi] = *(const bf16x8*)(XT + (m0 + mi * 16 + m) * ST1 + q * 8 + s * 32);
            #pragma unroll
            for (int ni = 0; ni < 8; ni++)
                bv[ni] = *(const bf16x8*)(XT + (ni * 16 + m) * ST1 + q * 8 + s * 32);
            #pragma unroll
            for (int mi = 0; mi < 2; mi++)
                #pragma unroll
                for (int ni = 0; ni < 8; ni++)
                    acc[mi][ni] = __builtin_amdgcn_mfma_f32_16x16x32_bf16(av[mi], bv[ni], acc[mi][ni], 0, 0, 0);
        }
    }

    // Row-major bf16 store. C/D layout: col=lane&15, row=q*4+reg (m89/m91).
    unsigned short* pp = part + (size_t)blk * (D * D);
    #pragma unroll
    for (int mi = 0; mi < 2; mi++)
        #pragma unroll
        for (int ni = 0; ni < 8; ni++) {
            const int row0 = m0 + mi * 16 + q * 4;
            const int col = ni * 16 + m;
            #pragma unroll
            for (int r = 0; r < 4; r++)
                pp[(size_t)(row0 + r) * D + col] = f2b(acc[mi][ni][r]);
        }
}

// ---------------- Stage 2: out = X * G, reducing partials inline -----------------
// 256 blocks x 256 threads. G-staging sums the batch's 8 bf16 partial slabs
// (uint4 loads, unpack+fp32 add, repack) straight into LDS — no reduce
// dispatch. MFMA structure unchanged from the proven round-4 kernel
// (G symmetric -> B-frag reads G row-major).
__global__ __launch_bounds__(256) void k_xg_r(const float* __restrict__ x,
                                              const unsigned short* __restrict__ part,
                                              float* __restrict__ out) {
    __shared__ unsigned short Xs[ROWS * S2];    // 17.4 KB
    __shared__ unsigned short Gs[D * S2];       // 34.8 KB
    const int blk = blockIdx.x;
    const int b = blk >> 6, chunk = blk & 63;
    const float* xp = x + ((size_t)b * T + (size_t)chunk * ROWS) * D;
    const unsigned short* pb = part + (size_t)b * SLABS * (D * D);
    const int tid = threadIdx.x;

    // X: fp32 global -> bf16 LDS (proven pattern).
    {
        const int dg = tid & 31, tr = tid >> 5;
        #pragma unroll
        for (int ii = 0; ii < 8; ii++) {
            const int t = tr + ii * 8;
            float4 v = ((const float4*)(xp + t * D))[dg];
            ushort4 pk;
            pk.x = f2b(v.x); pk.y = f2b(v.y); pk.z = f2b(v.z); pk.w = f2b(v.w);
            *(ushort4*)(Xs + t * S2 + dg * 4) = pk;
        }
    }
    // G: sum 8 bf16 partial slabs -> bf16 LDS.
    {
        const int f4 = tid & 15, r = tid >> 4;
        #pragma unroll
        for (int ii = 0; ii < 8; ii++) {
            const int row = r + ii * 16;
            const unsigned short* base = pb + (size_t)row * D + f4 * 8;
            float s[8];
            #pragma unroll
            for (int i = 0; i < 8; i++) s[i] = 0.f;
            #pragma unroll
            for (int c = 0; c < SLABS; c++) {
                uint4 gv = *(const uint4*)(base + (size_t)c * (D * D));
                s[0] += b2f_lo(gv.x); s[1] += b2f_hi(gv.x);
                s[2] += b2f_lo(gv.y); s[3] += b2f_hi(gv.y);
                s[4] += b2f_lo(gv.z); s[5] += b2f_hi(gv.z);
                s[6] += b2f_lo(gv.w); s[7] += b2f_hi(gv.w);
            }
            ushort4 lo4, hi4;
            lo4.x = f2b(s[0]); lo4.y = f2b(s[1]); lo4.z = f2b(s[2]); lo4.w = f2b(s[3]);
            hi4.x = f2b(s[4]); hi4.y = f2b(s[5]); hi4.z = f2b(s[6]); hi4.w = f2b(s[7]);
            *(ushort4*)(Gs + row * S2 + f4 * 8) = lo4;
            *(ushort4*)(Gs + row * S2 + f4 * 8 + 4) = hi4;
        }
    }
    __syncthreads();

    const int lane = tid & 63, w = tid >> 6;
    const int m = lane & 15, q = lane >> 4;

    f32x4 acc[8];
    #pragma unroll
    for (int ni = 0; ni < 8; ni++) acc[ni] = (f32x4){0.f, 0.f, 0.f, 0.f};

    const unsigned short* arow = Xs + (w * 16 + m) * S2 + q * 8;
    const unsigned short* brow = Gs + m * S2 + q * 8;

    #pragma unroll
    for (int s = 0; s < 4; s++) {
        bf16x8 a = *(const bf16x8*)(arow + s * 32);
        #pragma unroll
        for (int ni = 0; ni < 8; ni++) {
            bf16x8 bb = *(const bf16x8*)(brow + ni * 16 * S2 + s * 32);
            acc[ni] = __builtin_amdgcn_mfma_f32_16x16x32_bf16(a, bb, acc[ni], 0, 0, 0);
        }
    }

    float* op = out + ((size_t)b * T + (size_t)chunk * ROWS) * D;
    const int row0 = w * 16 + q * 4;
    #pragma unroll
    for (int ni = 0; ni < 8; ni++)
        #pragma unroll
        for (int r = 0; r < 4; r++)
            op[(row0 + r) * D + ni * 16 + m] = acc[ni][r];
}

extern "C" void kernel_launch(void* const* d_in, const int* in_sizes, int n_in,
                              void* d_out, int out_size, void* d_ws, size_t ws_size,
                              hipStream_t stream) {
    const float* x = (const float*)d_in[0];
    float* out = (float*)d_out;

    unsigned short* part = (unsigned short*)d_ws;   // BATCH*SLABS*D*D bf16 = 1 MB

    k_gram<<<BATCH * SLABS, 256, 0, stream>>>(x, part);
    k_xg_r<<<BATCH * 64, 256, 0, stream>>>(x, part, out);
}

// Round 8
// 70.595 us; speedup vs baseline: 2.5808x; 1.2702x over previous
//
#include <hip/hip_runtime.h>

#define BATCH 4
#define T 4096
#define D 128
#define CHUNKS 64              // gram chunks per batch (64 rows each)
#define ROWS 64                // rows per block tile
#define ST1 72                 // XT LDS stride in ushorts (144 B = 36 words ≡ 4 mod 32)
#define S2 136                 // stage-2 LDS stride in ushorts (272 B)

typedef __attribute__((ext_vector_type(4))) float f32x4;
typedef __attribute__((ext_vector_type(8))) short bf16x8;

__device__ __forceinline__ unsigned short f2b(float f) {
    unsigned u = __builtin_bit_cast(unsigned, f);
    u += 0x7FFFu + ((u >> 16) & 1u);
    return (unsigned short)(u >> 16);
}
__device__ __forceinline__ float b2f(unsigned short h) {
    return __builtin_bit_cast(float, (unsigned)h << 16);
}
__device__ __forceinline__ unsigned pk2(float a, float b) {
    return (unsigned)f2b(a) | ((unsigned)f2b(b) << 16);
}

// ---------------- Stage 1: partial Gram via bf16 MFMA -----------------
// 256 blocks x 256 threads (1/CU); block = (batch, 64-row chunk).
// LDS transpose staging (round-5 proven: float2 pair loads, packed uint
// writes, <=2-way banks). NEW vs round 5: partial G stored in raw
// C-fragment order — per-thread contiguous 128 B as 8 x uint4 (16 B)
// stores instead of 64 scattered 2 B stores. Layout+decode identical to
// the round-6 fused kernel's verified phase A/B.
__global__ __launch_bounds__(256) void k_gram(const float* __restrict__ x,
                                              unsigned short* __restrict__ part) {
    __shared__ unsigned short XT[D * ST1];   // 18.4 KB
    const int blk = blockIdx.x;
    const int b = blk >> 6, chunk = blk & 63;
    const float* xp = x + ((size_t)b * T + (size_t)chunk * ROWS) * D;
    const int tid = threadIdx.x;

    #pragma unroll
    for (int pass = 0; pass < 8; pass++) {
        const int slot = (tid >> 6) + 4 * pass;
        const int dd = 2 * (tid & 7) + 16 * (slot & 7);
        const int tpg = ((tid >> 3) & 7) + 8 * (slot >> 3);
        const int t = 2 * tpg;
        float2 f0 = *(const float2*)(xp + (size_t)t * D + dd);
        float2 f1 = *(const float2*)(xp + (size_t)(t + 1) * D + dd);
        *(unsigned*)(XT + dd * ST1 + 2 * tpg) = pk2(f0.x, f1.x);
        *(unsigned*)(XT + (dd + 1) * ST1 + 2 * tpg) = pk2(f0.y, f1.y);
    }
    __syncthreads();

    const int lane = tid & 63, w = tid >> 6;
    const int m = lane & 15, q = lane >> 4;
    const int m0 = w * 32;

    f32x4 acc[2][8];
    #pragma unroll
    for (int mi = 0; mi < 2; mi++)
        #pragma unroll
        for (int ni = 0; ni < 8; ni++) acc[mi][ni] = (f32x4){0.f, 0.f, 0.f, 0.f};

    #pragma unroll
    for (int s = 0; s < 2; s++) {
        bf16x8 av[2], bv[8];
        #pragma unroll
        for (int mi = 0; mi < 2; mi++)
            av[mi] = *(const bf16x8*)(XT + (m0 + mi * 16 + m) * ST1 + q * 8 + s * 32);
        #pragma unroll
        for (int ni = 0; ni < 8; ni++)
            bv[ni] = *(const bf16x8*)(XT + (ni * 16 + m) * ST1 + q * 8 + s * 32);
        #pragma unroll
        for (int mi = 0; mi < 2; mi++)
            #pragma unroll
            for (int ni = 0; ni < 8; ni++)
                acc[mi][ni] = __builtin_amdgcn_mfma_f32_16x16x32_bf16(av[mi], bv[ni], acc[mi][ni], 0, 0, 0);
    }

    // Raw-order store: sub = mi*32 + ni*4 + r; per-thread contiguous 128 B.
    unsigned short* pp = part + (size_t)blk * (D * D) + (size_t)tid * 64;
    #pragma unroll
    for (int j = 0; j < 8; j++) {
        const int mi = j >> 2, nj = (j & 3) * 2;
        uint4 v;
        v.x = pk2(acc[mi][nj][0],     acc[mi][nj][1]);
        v.y = pk2(acc[mi][nj][2],     acc[mi][nj][3]);
        v.z = pk2(acc[mi][nj + 1][0], acc[mi][nj + 1][1]);
        v.w = pk2(acc[mi][nj + 1][2], acc[mi][nj + 1][3]);
        *(uint4*)(pp + j * 8) = v;
    }
}

// ---------------- Stage 1b: reduce bf16 partials -> row-major bf16 G ----------
// 256 blocks x 256 threads; one G element/thread. Reads in storage order
// (coalesced: wave covers 128 B per chunk), decodes the fragment map
// (verified in round 6), writes row-major G.
__global__ __launch_bounds__(256) void k_reduce_g(const unsigned short* __restrict__ part,
                                                  unsigned short* __restrict__ g) {
    const int o = blockIdx.x * 256 + threadIdx.x;   // 0 .. BATCH*D*D-1
    const int ob = o >> 14, e = o & 16383;
    const unsigned short* p = part + ((size_t)ob * CHUNKS) * (D * D) + e;
    float s[8];
    #pragma unroll
    for (int i = 0; i < 8; i++) s[i] = 0.f;
    for (int c = 0; c < CHUNKS; c += 8) {
        #pragma unroll
        for (int i = 0; i < 8; i++)
            s[i] += b2f(p[(size_t)(c + i) * (D * D)]);
    }
    float sum = ((s[0] + s[1]) + (s[2] + s[3])) + ((s[4] + s[5]) + (s[6] + s[7]));
    // inverse fragment map: e -> (row, col)   [verified round 6]
    const int tg = e >> 6, sub = e & 63;
    const int gw = tg >> 6, gl = tg & 63, gm = gl & 15, gq = gl >> 4;
    const int mi = sub >> 5, ni = (sub >> 2) & 7, r = sub & 3;
    const int row = gw * 32 + mi * 16 + gq * 4 + r;
    const int col = ni * 16 + gm;
    g[(size_t)ob * (D * D) + row * D + col] = f2b(sum);
}

// ---------------- Stage 2: out = X * G via bf16 MFMA -----------------
// (unchanged — proven since round 4)
__global__ __launch_bounds__(256) void k_xg_mfma(const float* __restrict__ x,
                                                 const unsigned short* __restrict__ g,
                                                 float* __restrict__ out) {
    __shared__ unsigned short Xs[ROWS * S2];    // 17.4 KB
    __shared__ unsigned short Gs[D * S2];       // 34.8 KB
    const int blk = blockIdx.x;
    const int b = blk >> 6, chunk = blk & 63;
    const float* xp = x + ((size_t)b * T + (size_t)chunk * ROWS) * D;
    const unsigned short* gp = g + (size_t)b * (D * D);
    const int tid = threadIdx.x;

    {
        const int dg = tid & 31, tr = tid >> 5;
        #pragma unroll
        for (int ii = 0; ii < 8; ii++) {
            const int t = tr + ii * 8;
            float4 v = ((const float4*)(xp + t * D))[dg];
            ushort4 pk;
            pk.x = f2b(v.x); pk.y = f2b(v.y); pk.z = f2b(v.z); pk.w = f2b(v.w);
            *(ushort4*)(Xs + t * S2 + dg * 4) = pk;
        }
    }
    {
        const int f4 = tid & 15, r = tid >> 4;
        #pragma unroll
        for (int ii = 0; ii < 8; ii++) {
            const int row = r + ii * 16;
            uint4 gv = ((const uint4*)(gp + row * D))[f4];
            *(uint4*)(Gs + row * S2 + f4 * 8) = gv;
        }
    }
    __syncthreads();

    const int lane = tid & 63, w = tid >> 6;
    const int m = lane & 15, q = lane >> 4;

    f32x4 acc[8];
    #pragma unroll
    for (int ni = 0; ni < 8; ni++) acc[ni] = (f32x4){0.f, 0.f, 0.f, 0.f};

    const unsigned short* arow = Xs + (w * 16 + m) * S2 + q * 8;
    const unsigned short* brow = Gs + m * S2 + q * 8;

    #pragma unroll
    for (int s = 0; s < 4; s++) {
        bf16x8 a = *(const bf16x8*)(arow + s * 32);
        #pragma unroll
        for (int ni = 0; ni < 8; ni++) {
            bf16x8 bb = *(const bf16x8*)(brow + ni * 16 * S2 + s * 32);
            acc[ni] = __builtin_amdgcn_mfma_f32_16x16x32_bf16(a, bb, acc[ni], 0, 0, 0);
        }
    }

    float* op = out + ((size_t)b * T + (size_t)chunk * ROWS) * D;
    const int row0 = w * 16 + q * 4;
    #pragma unroll
    for (int ni = 0; ni < 8; ni++)
        #pragma unroll
        for (int r = 0; r < 4; r++)
            op[(row0 + r) * D + ni * 16 + m] = acc[ni][r];
}

extern "C" void kernel_launch(void* const* d_in, const int* in_sizes, int n_in,
                              void* d_out, int out_size, void* d_ws, size_t ws_size,
                              hipStream_t stream) {
    const float* x = (const float*)d_in[0];
    float* out = (float*)d_out;

    const size_t part_elems = (size_t)BATCH * CHUNKS * D * D;     // 4.19M bf16 (8.4 MB)
    unsigned short* part = (unsigned short*)d_ws;
    unsigned short* g = part + part_elems;                        // bf16 G, 128 KB

    k_gram<<<BATCH * CHUNKS, 256, 0, stream>>>(x, part);
    k_reduce_g<<<BATCH * D * D / 256, 256, 0, stream>>>(part, g);
    k_xg_mfma<<<BATCH * 64, 256, 0, stream>>>(x, g, out);
}